// Round 1
// baseline (363.468 us; speedup 1.0000x reference)
//
#include <hip/hip_runtime.h>

// Problem constants (fixed by setup_inputs): B=16, A=3, H=W=128, V=85.
// rows = B*A*H*W = 786432, each row: [box(4), obj, 80 class scores].
// Output 0: (rows, 7) = [box, obj, cls_id, conf] masked by conf > 0.25.
// Output 1: targets (16*50*5) — reference masking is an exact identity copy.

#define VROW 85
#define NCLS 80
#define OUTW 7
#define ROWS_PER_BLOCK 128
#define CONF_THRESHOLD 0.25f

__global__ __launch_bounds__(ROWS_PER_BLOCK) void yolo_post(
    const float* __restrict__ pred, float* __restrict__ out, int total_rows) {
    // LDS: staging for 128 rows x 85 floats = 43,520 B (also reused for output)
    __shared__ float lds[ROWS_PER_BLOCK * VROW];

    const int tid = threadIdx.x;
    const long long r0 = (long long)blockIdx.x * ROWS_PER_BLOCK;
    const int rows_here = min(ROWS_PER_BLOCK, total_rows - (int)r0);

    if (rows_here == ROWS_PER_BLOCK) {
        // Fast path: fully coalesced float4 staging.
        // Base byte offset r0*340 is a multiple of 16 (r0 multiple of 128).
        const float4* __restrict__ src =
            reinterpret_cast<const float4*>(pred + (size_t)r0 * VROW);
        float4* dst = reinterpret_cast<float4*>(lds);
        const int nvec = ROWS_PER_BLOCK * VROW / 4;  // 2720
        #pragma unroll 4
        for (int i = tid; i < nvec; i += ROWS_PER_BLOCK) dst[i] = src[i];
    } else {
        const float* src = pred + (size_t)r0 * VROW;
        const int nflt = rows_here * VROW;
        for (int i = tid; i < nflt; i += ROWS_PER_BLOCK) lds[i] = src[i];
    }
    __syncthreads();

    float o[OUTW];
    if (tid < rows_here) {
        // LDS row scan: stride 85 floats -> bank stride 21 (odd) -> 2-way only.
        const float* row = lds + tid * VROW;
        const float b0 = row[0], b1 = row[1], b2 = row[2], b3 = row[3];
        const float obj = row[4];
        float best = row[5];
        int besti = 0;
        #pragma unroll
        for (int c = 1; c < NCLS; ++c) {
            const float v = row[5 + c];
            if (v > best) { best = v; besti = c; }  // strict > keeps first max
        }
        const float conf = best * obj;
        const bool keep = conf > CONF_THRESHOLD;
        o[0] = keep ? b0 : 0.0f;
        o[1] = keep ? b1 : 0.0f;
        o[2] = keep ? b2 : 0.0f;
        o[3] = keep ? b3 : 0.0f;
        o[4] = keep ? obj : 0.0f;
        o[5] = keep ? (float)besti : 0.0f;
        o[6] = keep ? conf : 0.0f;
    }
    __syncthreads();  // done reading input LDS; reuse it for the output stage

    if (tid < rows_here) {
        float* orow = lds + tid * OUTW;  // stride 7 -> odd bank stride, 2-way
        #pragma unroll
        for (int k = 0; k < OUTW; ++k) orow[k] = o[k];
    }
    __syncthreads();

    if (rows_here == ROWS_PER_BLOCK) {
        // Coalesced vector store: base byte offset r0*28 is a multiple of 16.
        const float4* src = reinterpret_cast<const float4*>(lds);
        float4* __restrict__ dst =
            reinterpret_cast<float4*>(out + (size_t)r0 * OUTW);
        const int nvec = ROWS_PER_BLOCK * OUTW / 4;  // 224
        for (int i = tid; i < nvec; i += ROWS_PER_BLOCK) dst[i] = src[i];
    } else {
        float* dst = out + (size_t)r0 * OUTW;
        const int nflt = rows_here * OUTW;
        for (int i = tid; i < nflt; i += ROWS_PER_BLOCK) dst[i] = lds[i];
    }
}

// target_masked == targets exactly (all-zero rows map to zero == themselves).
__global__ void copy_targets(const float4* __restrict__ src,
                             float4* __restrict__ dst, int nvec) {
    const int i = blockIdx.x * blockDim.x + threadIdx.x;
    if (i < nvec) dst[i] = src[i];
}

extern "C" void kernel_launch(void* const* d_in, const int* in_sizes, int n_in,
                              void* d_out, int out_size, void* d_ws, size_t ws_size,
                              hipStream_t stream) {
    const float* output  = (const float*)d_in[0];   // (16,3,128,128,85)
    // d_in[1] = anchors — unused by the reference computation.
    const float* targets = (const float*)d_in[2];   // (16,50,5) = 4000 floats

    float* out = (float*)d_out;
    const int total_rows = in_sizes[0] / VROW;      // 786432
    const int pred_out_elems = total_rows * OUTW;   // 5,505,024

    const int nblocks = (total_rows + ROWS_PER_BLOCK - 1) / ROWS_PER_BLOCK;
    yolo_post<<<nblocks, ROWS_PER_BLOCK, 0, stream>>>(output, out, total_rows);

    const int tvec = in_sizes[2] / 4;               // 1000 float4s
    copy_targets<<<(tvec + 255) / 256, 256, 0, stream>>>(
        (const float4*)targets, (float4*)(out + pred_out_elems), tvec);
}

// Round 2
// 361.082 us; speedup vs baseline: 1.0066x; 1.0066x over previous
//
#include <hip/hip_runtime.h>

// B=16, A=3, H=W=128, V=85 -> rows = 786432, each row: [box(4), obj, 80 cls].
// Out0: (rows,7) = [box, obj, cls_id, conf] zeroed where conf <= 0.25.
// Out1: targets copy (identity: all-zero rows map to zero).

#define VROW 85
#define NCLS 80
#define OUTW 7
#define RPB 128            // rows per block == threads per block
#define CONF_THRESHOLD 0.25f

#define AS1 __attribute__((address_space(1)))
#define AS3 __attribute__((address_space(3)))

__global__ __launch_bounds__(RPB) void yolo_post(
    const float* __restrict__ pred, float* __restrict__ out, int total_rows,
    const float4* __restrict__ tgt_src, float4* __restrict__ tgt_dst, int tvec) {
    __shared__ float lds[RPB * VROW];   // 43,520 B -> 3 blocks/CU

    const int tid  = threadIdx.x;
    const int lane = tid & 63;
    const int wid  = tid >> 6;          // 0 or 1
    const long long r0 = (long long)blockIdx.x * RPB;
    const int rows_here = min(RPB, total_rows - (int)r0);

    if (rows_here == RPB) {
        // Async LDS-DMA staging: each wave issues 21 x 1KB loads back-to-back,
        // no VGPR round trip, no per-round vmcnt(0). Layout is contiguous in
        // lane order (dest = uniform base + lane*16), which matches exactly.
        const float4* srcv = reinterpret_cast<const float4*>(pred + (size_t)r0 * VROW);
        const int wbase = wid * 1360;   // 2720 float4s split across 2 waves
        #pragma unroll
        for (int it = 0; it < 21; ++it) {
            const int v = wbase + it * 64;   // wave-uniform float4 index
            __builtin_amdgcn_global_load_lds(
                (const AS1 void*)(srcv + v + lane),
                (AS3 void*)((AS3 float*)lds + (size_t)v * 4),
                16, 0, 0);
        }
        // tail: 16 float4s per wave (1360 = 21*64 + 16) — plain copy, zero-risk
        if (lane < 16) {
            const int v = wbase + 1344 + lane;
            *reinterpret_cast<float4*>(lds + (size_t)v * 4) = srcv[v];
        }
        // Overlap the tiny targets copy with the in-flight DMA (block 0 only).
        if (blockIdx.x == 0) {
            for (int i = tid; i < tvec; i += RPB) tgt_dst[i] = tgt_src[i];
        }
    } else {
        const float* src = pred + (size_t)r0 * VROW;
        const int nflt = rows_here * VROW;
        for (int i = tid; i < nflt; i += RPB) lds[i] = src[i];
    }
    __syncthreads();   // waits vmcnt(0) + lgkmcnt(0): DMA + tail both done

    if (tid < rows_here) {
        // LDS row scan: stride 85 floats -> odd bank stride -> 2-way (free).
        const float* row = lds + tid * VROW;
        const float b0 = row[0], b1 = row[1], b2 = row[2], b3 = row[3];
        const float obj = row[4];
        float best = row[5];
        int besti = 0;
        #pragma unroll
        for (int c = 1; c < NCLS; ++c) {
            const float v = row[5 + c];
            if (v > best) { best = v; besti = c; }  // strict > == jnp.argmax
        }
        const float conf = best * obj;
        const bool keep = conf > CONF_THRESHOLD;
        // Direct scattered stores: 7 x b32/lane; wave spans 1792 contiguous B,
        // L2 merges to full lines, HBM WRITE_SIZE stays minimal (~22 MB).
        float* dst = out + (size_t)(r0 + tid) * OUTW;
        dst[0] = keep ? b0 : 0.0f;
        dst[1] = keep ? b1 : 0.0f;
        dst[2] = keep ? b2 : 0.0f;
        dst[3] = keep ? b3 : 0.0f;
        dst[4] = keep ? obj : 0.0f;
        dst[5] = keep ? (float)besti : 0.0f;
        dst[6] = keep ? conf : 0.0f;
    }
}

extern "C" void kernel_launch(void* const* d_in, const int* in_sizes, int n_in,
                              void* d_out, int out_size, void* d_ws, size_t ws_size,
                              hipStream_t stream) {
    const float* output  = (const float*)d_in[0];   // (16,3,128,128,85)
    // d_in[1] = anchors — unused by the reference.
    const float* targets = (const float*)d_in[2];   // (16,50,5) = 4000 floats

    float* out = (float*)d_out;
    const int total_rows = in_sizes[0] / VROW;      // 786432
    const int pred_out_elems = total_rows * OUTW;   // 5,505,024 (x4 B, 16B-aligned)

    const int nblocks = (total_rows + RPB - 1) / RPB;   // 6144
    const int tvec = in_sizes[2] / 4;                    // 1000 float4s
    yolo_post<<<nblocks, RPB, 0, stream>>>(
        output, out, total_rows,
        (const float4*)targets, (float4*)(out + pred_out_elems), tvec);
}